// Round 3
// baseline (554.933 us; speedup 1.0000x reference)
//
#include <hip/hip_runtime.h>

// ---------- problem constants ----------
#define BB 4096
#define NN 25
#define DD 256
#define HH 8
#define DKH 32
#define MM (BB*NN)          // 102400

typedef __bf16 bf16;
typedef bf16 bf16x8 __attribute__((ext_vector_type(8)));
typedef bf16 bf16x4 __attribute__((ext_vector_type(4)));
typedef float f32x4 __attribute__((ext_vector_type(4)));
typedef _Float16 h16;
typedef h16 h16x2 __attribute__((ext_vector_type(2)));
typedef h16 h16x4 __attribute__((ext_vector_type(4)));
typedef h16 h16x8 __attribute__((ext_vector_type(8)));

// async global->LDS, 16B per lane, LDS dest = wave-uniform base + lane*16
__device__ __forceinline__ void async_load16(const void* g, void* l) {
  __builtin_amdgcn_global_load_lds(
      (const __attribute__((address_space(1))) unsigned int*)g,
      (__attribute__((address_space(3))) unsigned int*)l, 16, 0, 0);
}

#define SCHED_FENCE() __builtin_amdgcn_sched_barrier(0)
#define BARRIER() do { SCHED_FENCE(); __builtin_amdgcn_s_barrier(); SCHED_FENCE(); } while (0)

// ---------- prep: padded bf16 x  x_pad[b][j][d], j in [0,27): j=0,26 zero, else x[b][j-1][d]
__global__ __launch_bounds__(256) void k_prep_xpad(const float* __restrict__ x,
                                                   bf16* __restrict__ xpad) {
  int idx = (blockIdx.x * 256 + threadIdx.x) * 8;
  const int total = BB * 27 * 256;
  if (idx >= total) return;
  int b = idx / (27 * 256);
  int rem = idx - b * 27 * 256;
  int j = rem >> 8;
  int d = rem & 255;
  bf16x8 o;
  if (j >= 1 && j <= 25) {
    const float* src = x + ((b * 25 + (j - 1)) * 256 + d);
    #pragma unroll
    for (int t = 0; t < 8; ++t) o[t] = (bf16)src[t];
  } else {
    #pragma unroll
    for (int t = 0; t < 8; ++t) o[t] = (bf16)0.0f;
  }
  *(bf16x8*)(xpad + idx) = o;
}

// ---------- prep: Wt[768][768] (B^T for qkv gemm), wo bf16, masked bias mb[h][i][32] ----------
__global__ __launch_bounds__(256) void k_prep_misc(
    const float* __restrict__ wq, const float* __restrict__ wk, const float* __restrict__ wv,
    const float* __restrict__ rel, const float* __restrict__ lb, const float* __restrict__ wo,
    const void* __restrict__ adj_raw,
    bf16* __restrict__ Wt, bf16* __restrict__ woB, float* __restrict__ mb) {
  const int NWT = 768 * 768;
  const int NWO = 256 * 256;
  const int NMB = HH * NN * 32;
  const int total = NWT + NWO + NMB;
  for (int i = blockIdx.x * blockDim.x + threadIdx.x; i < total; i += gridDim.x * blockDim.x) {
    if (i < NWT) {
      int j = i / 768, kk = i - j * 768;
      int proj = j >> 8, jo = j & 255;
      int tap = kk >> 8, di = kk & 255;
      const float* w = (proj == 0) ? wq : ((proj == 1) ? wk : wv);
      Wt[i] = (bf16)w[(jo * 256 + di) * 3 + tap];   // w[d_out][d_in][tap]
    } else if (i < NWT + NWO) {
      int t = i - NWT;
      woB[t] = (bf16)wo[t];                          // wo[j][d] is already B^T layout
    } else {
      int t = i - NWT - NWO;
      int pair = t >> 5;          // h*25 + i
      int m = t & 31;
      int h = pair / 25, ii = pair - h * 25;
      float v = -1e30f;
      if (m < 25) {
        // detect whether adj is uint8 (bool) or int32
        const unsigned char* bytes = (const unsigned char*)adj_raw;
        bool u8 = false;
        for (int s = 0; s < 625; ++s) {
          if ((s & 3) && bytes[s]) { u8 = true; break; }
        }
        int amask = u8 ? (bytes[ii * 25 + m] ? 1 : 0)
                       : (((const int*)adj_raw)[ii * 25 + m] ? 1 : 0);
        if (amask)
          v = rel[(ii - m + 24) * HH + h] + lb[h * 625 + ii * 25 + m];
      }
      mb[t] = v;
    }
  }
}

// ---------- QKV GEMM, 256x256 tile, pipelined reads + derived counted waits ----------
// C[102400][768] = A_gather[102400][768] * Wt^T.  BM=BN=256, BK=64, 8 waves (2Mx4N),
// LDS = 2 dbuf x (A 256x64 + B 256x64) bf16 = 128 KiB -> 1 block/CU, 2 waves/SIMD.
// Schedule per K-tile u (buf c=u&1), ds_reads issued ONE MFMA-cluster ahead so the
// compiler emits counted lgkmcnt waits (T4 for the LDS counter; m218/m232 lesson):
//   P0: RD[bHi(c)]          ; MFMA(0,0) aLo x bLo   (aLo/bLo pre-issued at u-1 P3)
//   P1: RD[aHi(c)]          ; MFMA(0,1) aLo x bHi
//   P2: BAR (B-region safe) ; stage B(u+2)->c ; MFMA(1,0) aHi x bLo
//   P3: vmcnt(4) BAR (arrival + A-region safe); stage A(u+2)->c;
//       RD[aLo,bLo (c^1)]   ; MFMA(1,1) aHi x bHi   (reads drain under the MFMAs)
// vmcnt never drains to 0 in steady state (12 in flight -> vmcnt(4) retires tile
// u+1's 8, keeps B(u+2) flying). 2 barriers per K-tile instead of 9.
// LDS XOR-swizzle (T2) unchanged: pre-swizzled global source + swizzled ds_read.
__global__ __launch_bounds__(512, 2) void k_qkv_gemm8(const bf16* __restrict__ xpad,
                                                      const bf16* __restrict__ Wt,
                                                      bf16* __restrict__ conv) {
  __shared__ bf16 Ab[2][256 * 64];
  __shared__ bf16 Bb[2][256 * 64];

  // XCD-aware bijective swizzle (1200 % 8 == 0)
  const int L = blockIdx.x;
  const int sw = (L & 7) * 150 + (L >> 3);
  const int n0 = (sw % 3) * 256;
  const int m0 = (sw / 3) * 256;

  const int tid = threadIdx.x;
  const int lane = tid & 63, wave = tid >> 6;
  const int t16 = lane & 15, quad = lane >> 4;
  const int wr = wave >> 2, wc = wave & 3;

  // ---- staging addresses: lane covers (row = q*64 + tid/8, 16B col (tid%8)*16) ----
  const int srow = tid >> 3;                                    // 0..63
  const int sc = ((tid & 7) << 4) ^ ((srow & 7) << 4);          // pre-swizzled byte col
  int aOff[4], bOff[4];
  #pragma unroll
  for (int q = 0; q < 4; ++q) {
    int row = q * 64 + srow;
    int gm = m0 + row;
    int b = gm / 25;
    int n = gm - b * 25;
    aOff[q] = (b * 27 + n) * 512 + sc;                          // bytes into xpad
    bOff[q] = (n0 + row) * 1536 + sc;                           // bytes into Wt
  }

  // ---- ds_read fragment offsets (elements), same XOR swizzle ----
  const int axr = (t16 & 7) << 3;                               // element-space swizzle
  int aoffs[2], boffs[2];
  #pragma unroll
  for (int kk = 0; kk < 2; ++kk) {
    aoffs[kk] = (wr * 128 + t16) * 64 + ((kk * 32 + quad * 8) ^ axr);
    boffs[kk] = (wc * 64 + t16) * 64 + ((kk * 32 + quad * 8) ^ axr);
  }

  f32x4 acc[8][4];
  #pragma unroll
  for (int i = 0; i < 8; ++i)
    #pragma unroll
    for (int j = 0; j < 4; ++j) acc[i][j] = (f32x4){0.f, 0.f, 0.f, 0.f};

  // stage helpers: 4 global_load_lds per wave per region per tile (B first, then A)
  #define ST_B(bufi, tt) do {                                              \
    char* lb_ = (char*)&Bb[bufi][0] + wave * 1024;                         \
    _Pragma("unroll")                                                      \
    for (int q_ = 0; q_ < 4; ++q_)                                         \
      async_load16((const char*)Wt + bOff[q_] + (tt) * 128, lb_ + q_ * 8192); \
  } while (0)
  #define ST_A(bufi, tt) do {                                              \
    char* la_ = (char*)&Ab[bufi][0] + wave * 1024;                         \
    const int ka_ = ((tt) >> 2) * 512 + ((tt) & 3) * 128;                  \
    _Pragma("unroll")                                                      \
    for (int q_ = 0; q_ < 4; ++q_)                                         \
      async_load16((const char*)xpad + aOff[q_] + ka_, la_ + q_ * 8192);   \
  } while (0)

  // ---- prologue: stage tiles 0 and 1 ----
  ST_B(0, 0); ST_A(0, 0);
  ST_B(1, 1); ST_A(1, 1);
  asm volatile("s_waitcnt vmcnt(8)" ::: "memory");   // tile 0 resident; tile 1 in flight
  SCHED_FENCE();
  BARRIER();

  bf16x8 aLo[8], aHi[8], bLo[4], bHi[4];
  // pre-issue tile 0's P0 fragments (aLo, bLo from buf 0)
  {
    const bf16* Ac = &Ab[0][0];
    const bf16* Bc = &Bb[0][0];
    #pragma unroll
    for (int i = 0; i < 4; ++i)
      #pragma unroll
      for (int kk = 0; kk < 2; ++kk)
        aLo[i * 2 + kk] = *(const bf16x8*)(Ac + aoffs[kk] + i * 1024);
    #pragma unroll
    for (int j = 0; j < 2; ++j)
      #pragma unroll
      for (int kk = 0; kk < 2; ++kk)
        bLo[j * 2 + kk] = *(const bf16x8*)(Bc + boffs[kk] + j * 1024);
  }
  SCHED_FENCE();

  for (int u = 0; u < 12; ++u) {
    const int buf = u & 1;
    const bf16* Ac = &Ab[buf][0];
    const bf16* Bc = &Bb[buf][0];
    const bf16* Ac2 = &Ab[buf ^ 1][0];
    const bf16* Bc2 = &Bb[buf ^ 1][0];
    const int st = u + 2;

    // ===== P0: issue bHi reads; MFMA quadrant (0,0) on aLo x bLo =====
    #pragma unroll
    for (int j = 0; j < 2; ++j)
      #pragma unroll
      for (int kk = 0; kk < 2; ++kk)
        bHi[j * 2 + kk] = *(const bf16x8*)(Bc + boffs[kk] + (2 + j) * 1024);
    SCHED_FENCE();
    __builtin_amdgcn_s_setprio(1);
    #pragma unroll
    for (int i = 0; i < 4; ++i)
      #pragma unroll
      for (int j = 0; j < 2; ++j)
        #pragma unroll
        for (int kk = 0; kk < 2; ++kk)
          acc[i][j] = __builtin_amdgcn_mfma_f32_16x16x32_bf16(
              aLo[i * 2 + kk], bLo[j * 2 + kk], acc[i][j], 0, 0, 0);
    __builtin_amdgcn_s_setprio(0);
    SCHED_FENCE();

    // ===== P1: issue aHi reads; MFMA quadrant (0,1) on aLo x bHi =====
    #pragma unroll
    for (int i = 0; i < 4; ++i)
      #pragma unroll
      for (int kk = 0; kk < 2; ++kk)
        aHi[i * 2 + kk] = *(const bf16x8*)(Ac + aoffs[kk] + (4 + i) * 1024);
    SCHED_FENCE();
    __builtin_amdgcn_s_setprio(1);
    #pragma unroll
    for (int i = 0; i < 4; ++i)
      #pragma unroll
      for (int j = 0; j < 2; ++j)
        #pragma unroll
        for (int kk = 0; kk < 2; ++kk)
          acc[i][2 + j] = __builtin_amdgcn_mfma_f32_16x16x32_bf16(
              aLo[i * 2 + kk], bHi[j * 2 + kk], acc[i][2 + j], 0, 0, 0);
    __builtin_amdgcn_s_setprio(0);
    SCHED_FENCE();

    // ===== P2: barrier (all B(c) reads retired by MFMA(0,0)/(0,1)); stage B(u+2);
    //           MFMA quadrant (1,0) on aHi x bLo =====
    BARRIER();
    if (st < 12) ST_B(buf, st);
    SCHED_FENCE();
    __builtin_amdgcn_s_setprio(1);
    #pragma unroll
    for (int i = 0; i < 4; ++i)
      #pragma unroll
      for (int j = 0; j < 2; ++j)
        #pragma unroll
        for (int kk = 0; kk < 2; ++kk)
          acc[4 + i][j] = __builtin_amdgcn_mfma_f32_16x16x32_bf16(
              aHi[i * 2 + kk], bLo[j * 2 + kk], acc[4 + i][j], 0, 0, 0);
    __builtin_amdgcn_s_setprio(0);
    SCHED_FENCE();

    // ===== P3: counted vmcnt + barrier (arrival of tile u+1, A(c) region safe);
    //           stage A(u+2); pre-issue next tile's aLo/bLo; MFMA quadrant (1,1) =====
    if (u < 11) {
      if (u < 10) {
        asm volatile("s_waitcnt vmcnt(4)" ::: "memory");  // retire tile u+1's 8, keep B(u+2)
      } else {
        asm volatile("s_waitcnt vmcnt(0)" ::: "memory");  // last arrival (tile 11)
      }
      SCHED_FENCE();
      BARRIER();
      if (st < 12) ST_A(buf, st);
      #pragma unroll
      for (int i = 0; i < 4; ++i)
        #pragma unroll
        for (int kk = 0; kk < 2; ++kk)
          aLo[i * 2 + kk] = *(const bf16x8*)(Ac2 + aoffs[kk] + i * 1024);
      #pragma unroll
      for (int j = 0; j < 2; ++j)
        #pragma unroll
        for (int kk = 0; kk < 2; ++kk)
          bLo[j * 2 + kk] = *(const bf16x8*)(Bc2 + boffs[kk] + j * 1024);
      SCHED_FENCE();
    }
    __builtin_amdgcn_s_setprio(1);
    #pragma unroll
    for (int i = 0; i < 4; ++i)
      #pragma unroll
      for (int j = 0; j < 2; ++j)
        #pragma unroll
        for (int kk = 0; kk < 2; ++kk)
          acc[4 + i][2 + j] = __builtin_amdgcn_mfma_f32_16x16x32_bf16(
              aHi[i * 2 + kk], bHi[j * 2 + kk], acc[4 + i][2 + j], 0, 0, 0);
    __builtin_amdgcn_s_setprio(0);
    SCHED_FENCE();
  }
  #undef ST_A
  #undef ST_B

  // ---- epilogue: C write (f32 acc -> bf16), per wave a 128x64 sub-tile ----
  #pragma unroll
  for (int i = 0; i < 8; ++i)
    #pragma unroll
    for (int j = 0; j < 4; ++j) {
      const int col = n0 + wc * 64 + j * 16 + t16;
      #pragma unroll
      for (int r = 0; r < 4; ++r) {
        const int rowm = m0 + wr * 128 + i * 16 + quad * 4 + r;
        conv[(size_t)rowm * 768 + col] = (bf16)acc[i][j][r];
      }
    }
}

// ---------- fused LN + residual + masked attention, one block per batch ----------
__global__ __launch_bounds__(256, 4) void k_attn3(
    const bf16* __restrict__ conv, const float* __restrict__ x,
    const float* __restrict__ gq, const float* __restrict__ bq,
    const float* __restrict__ gk, const float* __restrict__ bk,
    const float* __restrict__ gv, const float* __restrict__ bv,
    const float* __restrict__ mb, bf16* __restrict__ attnout) {
  __shared__ bf16 Cs[19456];     // 38912 B: 38 x 1024B chunks (25*768=19200 used)
  const int b = blockIdx.x;
  const int tid = threadIdx.x;
  const int wave = tid >> 6, lane = tid & 63;

  // blanket stage of the batch slab (contiguous 38400 B, over-staged to 38912 B)
  const char* slab = (const char*)(conv + (size_t)b * 19200);
  for (int c = wave; c < 38; c += 4)
    async_load16(slab + c * 1024 + lane * 16, (char*)Cs + c * 1024);
  asm volatile("s_waitcnt vmcnt(0)" ::: "memory");
  __syncthreads();

  // phase 1: LN + residual for 75 rows (node n, proj p), one wave per row
  for (int rowi = wave; rowi < 75; rowi += 4) {
    int n = rowi / 3;
    int p = rowi - n * 3;
    const int off = n * 768 + p * 256 + lane * 4;
    bf16x4 cv = *(const bf16x4*)(Cs + off);
    float v0 = (float)cv[0], v1 = (float)cv[1], v2 = (float)cv[2], v3 = (float)cv[3];
    float s = v0 + v1 + v2 + v3;
    float ss = v0 * v0 + v1 * v1 + v2 * v2 + v3 * v3;
    #pragma unroll
    for (int o = 32; o; o >>= 1) {
      s += __shfl_xor(s, o);
      ss += __shfl_xor(ss, o);
    }
    float mu = s * (1.0f / 256.0f);
    float var = ss * (1.0f / 256.0f) - mu * mu;
    float rs = rsqrtf(var + 1e-5f);
    const float* gsel = (p == 0) ? gq : ((p == 1) ? gk : gv);
    const float* bsel = (p == 0) ? bq : ((p == 1) ? bk : bv);
    const int dbase = lane * 4;
    f32x4 gg = *(const f32x4*)(gsel + dbase);
    f32x4 b2 = *(const f32x4*)(bsel + dbase);
    f32x4 xv = *(const f32x4*)(x + ((size_t)(b * 25 + n)) * 256 + dbase);
    h16x4 o;
    o[0] = (h16)((v0 - mu) * rs * gg[0] + b2[0] + xv[0]);
    o[1] = (h16)((v1 - mu) * rs * gg[1] + b2[1] + xv[1]);
    o[2] = (h16)((v2 - mu) * rs * gg[2] + b2[2] + xv[2]);
    o[3] = (h16)((v3 - mu) * rs * gg[3] + b2[3] + xv[3]);
    *(h16x4*)((h16*)Cs + off) = o;   // in-place bf16 -> f16, per-lane 8B
  }
  __syncthreads();

  // phase 2: one lane per (head, query-node)
  const h16* Ch = (const h16*)Cs;
  if (tid < HH * NN) {
    const int h = tid / 25;
    const int i = tid - h * 25;

    h16x2 qv[16];
    const h16x2* qp = (const h16x2*)(Ch + i * 768 + h * 32);
    #pragma unroll
    for (int c = 0; c < 16; ++c) qv[c] = qp[c];

    float mrow[28];
    const float* mbp = mb + (h * 25 + i) * 32;
    #pragma unroll
    for (int c = 0; c < 7; ++c) *(f32x4*)(mrow + c * 4) = *(const f32x4*)(mbp + c * 4);

    const float scale = 0.17677669529663687f;  // 1/sqrt(32)
    float sc[25];
    #pragma unroll
    for (int m = 0; m < 25; ++m) {
      const h16x2* kr = (const h16x2*)(Ch + m * 768 + 256 + h * 32);
      float d = 0.f;
      #pragma unroll
      for (int c = 0; c < 16; ++c)
        d = __builtin_amdgcn_fdot2(qv[c], kr[c], d, false);
      sc[m] = d * scale + mrow[m];
    }

    float mx = sc[0];
    #pragma unroll
    for (int m = 1; m < 25; ++m) mx = fmaxf(mx, sc[m]);
    float sum = 0.f;
    #pragma unroll
    for (int m = 0; m < 25; ++m) { sc[m] = __expf(sc[m] - mx); sum += sc[m]; }
    const float inv = 1.0f / sum;

    h16x2 acc[16];
    #pragma unroll
    for (int j = 0; j < 16; ++j) acc[j] = (h16x2){(h16)0.f, (h16)0.f};
    #pragma unroll
    for (int m = 0; m < 25; ++m) {
      h16 w = (h16)(sc[m] * inv);
      h16x2 wp = {w, w};
      const h16x2* vr = (const h16x2*)(Ch + m * 768 + 512 + h * 32);
      #pragma unroll
      for (int j = 0; j < 16; ++j)
        acc[j] = wp * vr[j] + acc[j];   // v_pk_fma_f16
    }

    bf16* dst = attnout + ((size_t)b * 25 + i) * 256 + h * 32;
    #pragma unroll
    for (int c = 0; c < 4; ++c) {
      bf16x8 o;
      #pragma unroll
      for (int j = 0; j < 4; ++j) {
        o[2 * j]     = (bf16)(float)acc[c * 4 + j][0];
        o[2 * j + 1] = (bf16)(float)acc[c * 4 + j][1];
      }
      *(bf16x8*)(dst + c * 8) = o;
    }
  }
}

// ---------- output projection: out = attn @ wo^T + bo (f32 out), swizzled grid ----------
__global__ __launch_bounds__(256) void k_outproj(const bf16* __restrict__ attn,
                                                 const bf16* __restrict__ woB,
                                                 const float* __restrict__ bo,
                                                 float* __restrict__ out) {
  __shared__ bf16 As[128 * 32];
  __shared__ bf16 Bs[128 * 32];
  const int L = blockIdx.x;
  const int X = L & 7;
  const int t = L >> 3;                  // [0,200)
  const int n0 = (t & 1) * 128;
  const int m0 = (X + 8 * (t >> 1)) * 128;
  const int tid = threadIdx.x;
  const int wave = tid >> 6, lane = tid & 63;
  const int quad = lane >> 4, t16 = lane & 15;
  const int wr = wave >> 1, wc = wave & 1;

  f32x4 acc[4][4];
  #pragma unroll
  for (int i = 0; i < 4; ++i)
    #pragma unroll
    for (int j = 0; j < 4; ++j) acc[i][j] = (f32x4){0.f, 0.f, 0.f, 0.f};

  const bf16* baseA[2];
  const bf16* baseB[2];
  #pragma unroll
  for (int r = 0; r < 2; ++r) {
    int c = r * 256 + wave * 64 + lane;
    int row = c >> 2, sub = c & 3;
    baseA[r] = attn + (m0 + row) * 256 + sub * 8;
    baseB[r] = woB + (n0 + row) * 256 + sub * 8;
  }

  for (int ks = 0; ks < 256; ks += 32) {
    #pragma unroll
    for (int r = 0; r < 2; ++r)
      async_load16(baseA[r] + ks, As + (r * 256 + wave * 64) * 8);
    #pragma unroll
    for (int r = 0; r < 2; ++r)
      async_load16(baseB[r] + ks, Bs + (r * 256 + wave * 64) * 8);
    asm volatile("s_waitcnt vmcnt(0)" ::: "memory");
    __syncthreads();

    bf16x8 af[4], bfr[4];
    #pragma unroll
    for (int i = 0; i < 4; ++i)
      af[i] = *(const bf16x8*)(As + (wr * 64 + i * 16 + t16) * 32 + quad * 8);
    #pragma unroll
    for (int j = 0; j < 4; ++j)
      bfr[j] = *(const bf16x8*)(Bs + (wc * 64 + j * 16 + t16) * 32 + quad * 8);
    #pragma unroll
    for (int i = 0; i < 4; ++i)
      #pragma unroll
      for (int j = 0; j < 4; ++j)
        acc[i][j] = __builtin_amdgcn_mfma_f32_16x16x32_bf16(af[i], bfr[j], acc[i][j], 0, 0, 0);
    __syncthreads();
  }

  #pragma unroll
  for (int j = 0; j < 4; ++j) {
    int col = n0 + wc * 64 + j * 16 + t16;
    float bb = bo[col];
    #pragma unroll
    for (int i = 0; i < 4; ++i)
      #pragma unroll
      for (int r = 0; r < 4; ++r) {
        int rowm = m0 + wr * 64 + i * 16 + quad * 4 + r;
        out[rowm * 256 + col] = acc[i][j][r] + bb;
      }
  }
}

extern "C" void kernel_launch(void* const* d_in, const int* in_sizes, int n_in,
                              void* d_out, int out_size, void* d_ws, size_t ws_size,
                              hipStream_t stream) {
  (void)in_sizes; (void)n_in; (void)out_size; (void)ws_size;
  const float* x  = (const float*)d_in[0];
  const void*  adj = d_in[1];
  const float* wq = (const float*)d_in[2];
  const float* wk = (const float*)d_in[3];
  const float* wv = (const float*)d_in[4];
  const float* gq = (const float*)d_in[5];
  const float* bq = (const float*)d_in[6];
  const float* gk = (const float*)d_in[7];
  const float* bk = (const float*)d_in[8];
  const float* gv = (const float*)d_in[9];
  const float* bv = (const float*)d_in[10];
  const float* rel = (const float*)d_in[11];
  const float* lb = (const float*)d_in[12];
  const float* wo = (const float*)d_in[13];
  const float* bo = (const float*)d_in[14];
  float* out = (float*)d_out;

  char* ws = (char*)d_ws;
  size_t off = 0;
  auto alloc = [&](size_t bytes) -> void* {
    void* p = ws + off;
    off += (bytes + 255) & ~(size_t)255;
    return p;
  };
  bf16* xpad = (bf16*)alloc((size_t)BB * 27 * 256 * 2);    // 56.6 MB
  bf16* conv = (bf16*)alloc((size_t)MM * 768 * 2);         // 157.3 MB
  bf16* attn = (bf16*)alloc((size_t)MM * 256 * 2);         // 52.4 MB
  bf16* Wt   = (bf16*)alloc((size_t)768 * 768 * 2);
  bf16* woB  = (bf16*)alloc((size_t)256 * 256 * 2);
  float* mb  = (float*)alloc((size_t)HH * NN * 32 * 4);

  hipLaunchKernelGGL(k_prep_xpad, dim3(13824), dim3(256), 0, stream, x, xpad);
  hipLaunchKernelGGL(k_prep_misc, dim3(512), dim3(256), 0, stream,
                     wq, wk, wv, rel, lb, wo, adj, Wt, woB, mb);
  hipLaunchKernelGGL(k_qkv_gemm8, dim3(1200), dim3(512), 0, stream, xpad, Wt, conv);
  hipLaunchKernelGGL(k_attn3, dim3(4096), dim3(256), 0, stream,
                     conv, x, gq, bq, gk, bk, gv, bv, mb, attn);
  hipLaunchKernelGGL(k_outproj, dim3(1600), dim3(256), 0, stream, attn, woB, bo, out);
}

// Round 4
// 521.640 us; speedup vs baseline: 1.0638x; 1.0638x over previous
//
#include <hip/hip_runtime.h>

// ---------- problem constants ----------
#define BB 4096
#define NN 25
#define DD 256
#define HH 8
#define DKH 32
#define MM (BB*NN)          // 102400

typedef __bf16 bf16;
typedef bf16 bf16x8 __attribute__((ext_vector_type(8)));
typedef bf16 bf16x4 __attribute__((ext_vector_type(4)));
typedef float f32x4 __attribute__((ext_vector_type(4)));
typedef _Float16 h16;
typedef h16 h16x2 __attribute__((ext_vector_type(2)));
typedef h16 h16x4 __attribute__((ext_vector_type(4)));
typedef h16 h16x8 __attribute__((ext_vector_type(8)));

// async global->LDS, 16B per lane, LDS dest = wave-uniform base + lane*16
__device__ __forceinline__ void async_load16(const void* g, void* l) {
  __builtin_amdgcn_global_load_lds(
      (const __attribute__((address_space(1))) unsigned int*)g,
      (__attribute__((address_space(3))) unsigned int*)l, 16, 0, 0);
}

#define SCHED_FENCE() __builtin_amdgcn_sched_barrier(0)
#define BARRIER() do { SCHED_FENCE(); __builtin_amdgcn_s_barrier(); SCHED_FENCE(); } while (0)

// ---------- merged prep: xpad (blocks 0..13823) + tables (blocks 13824..14335) ----------
// xpad[b][j][d], j in [0,27): j=0,26 zero, else x[b][j-1][d]  (bf16)
// Wt[768][768]: B^T for qkv gemm.  mb[h][i][32]: masked rel+local bias.
// woF: outproj B in MFMA-fragment order: elem e = ((ks*16+nt)*64+lane)*8+c
//      holds wo[col][k] with col=nt*16+(lane&15), k=ks*32+(lane>>4)*8+c  (f16)
__global__ __launch_bounds__(256) void k_prep(
    const float* __restrict__ x, bf16* __restrict__ xpad,
    const float* __restrict__ wq, const float* __restrict__ wk, const float* __restrict__ wv,
    const float* __restrict__ rel, const float* __restrict__ lb, const float* __restrict__ wo,
    const void* __restrict__ adj_raw,
    bf16* __restrict__ Wt, h16* __restrict__ woF, float* __restrict__ mb) {
  if (blockIdx.x < 13824) {
    int idx = (blockIdx.x * 256 + threadIdx.x) * 8;
    const int total = BB * 27 * 256;
    if (idx >= total) return;
    int b = idx / (27 * 256);
    int rem = idx - b * 27 * 256;
    int j = rem >> 8;
    int d = rem & 255;
    bf16x8 o;
    if (j >= 1 && j <= 25) {
      const float* src = x + ((b * 25 + (j - 1)) * 256 + d);
      #pragma unroll
      for (int t = 0; t < 8; ++t) o[t] = (bf16)src[t];
    } else {
      #pragma unroll
      for (int t = 0; t < 8; ++t) o[t] = (bf16)0.0f;
    }
    *(bf16x8*)(xpad + idx) = o;
    return;
  }
  // ---- table part: 512 blocks grid-stride ----
  const int NWT = 768 * 768;
  const int NMB = HH * NN * 32;
  const int NWF = 8 * 16 * 64 * 8;      // 65536
  const int total = NWT + NMB + NWF;
  for (int i = (blockIdx.x - 13824) * 256 + threadIdx.x; i < total; i += 512 * 256) {
    if (i < NWT) {
      int j = i / 768, kk = i - j * 768;
      int proj = j >> 8, jo = j & 255;
      int tap = kk >> 8, di = kk & 255;
      const float* w = (proj == 0) ? wq : ((proj == 1) ? wk : wv);
      Wt[i] = (bf16)w[(jo * 256 + di) * 3 + tap];   // w[d_out][d_in][tap]
    } else if (i < NWT + NMB) {
      int t = i - NWT;
      int pair = t >> 5;          // h*25 + i
      int m = t & 31;
      int h = pair / 25, ii = pair - h * 25;
      float v = -1e30f;
      if (m < 25) {
        // detect whether adj is uint8 (bool) or int32
        const unsigned char* bytes = (const unsigned char*)adj_raw;
        bool u8 = false;
        for (int s = 0; s < 625; ++s) {
          if ((s & 3) && bytes[s]) { u8 = true; break; }
        }
        int amask = u8 ? (bytes[ii * 25 + m] ? 1 : 0)
                       : (((const int*)adj_raw)[ii * 25 + m] ? 1 : 0);
        if (amask)
          v = rel[(ii - m + 24) * HH + h] + lb[h * 625 + ii * 25 + m];
      }
      mb[t] = v;
    } else {
      int e = i - NWT - NMB;
      int c = e & 7, ln = (e >> 3) & 63, nt = (e >> 9) & 15, ks = e >> 13;
      int col = nt * 16 + (ln & 15);
      int k = ks * 32 + (ln >> 4) * 8 + c;
      woF[e] = (h16)wo[col * 256 + k];
    }
  }
}

// ---------- QKV GEMM, 256x256 tile, pipelined reads + derived counted waits ----------
// (unchanged from round 3 — isolating the attn/outproj fusion this round)
__global__ __launch_bounds__(512, 2) void k_qkv_gemm8(const bf16* __restrict__ xpad,
                                                      const bf16* __restrict__ Wt,
                                                      bf16* __restrict__ conv) {
  __shared__ bf16 Ab[2][256 * 64];
  __shared__ bf16 Bb[2][256 * 64];

  const int L = blockIdx.x;
  const int sw = (L & 7) * 150 + (L >> 3);
  const int n0 = (sw % 3) * 256;
  const int m0 = (sw / 3) * 256;

  const int tid = threadIdx.x;
  const int lane = tid & 63, wave = tid >> 6;
  const int t16 = lane & 15, quad = lane >> 4;
  const int wr = wave >> 2, wc = wave & 3;

  const int srow = tid >> 3;                                    // 0..63
  const int sc = ((tid & 7) << 4) ^ ((srow & 7) << 4);          // pre-swizzled byte col
  int aOff[4], bOff[4];
  #pragma unroll
  for (int q = 0; q < 4; ++q) {
    int row = q * 64 + srow;
    int gm = m0 + row;
    int b = gm / 25;
    int n = gm - b * 25;
    aOff[q] = (b * 27 + n) * 512 + sc;                          // bytes into xpad
    bOff[q] = (n0 + row) * 1536 + sc;                           // bytes into Wt
  }

  const int axr = (t16 & 7) << 3;                               // element-space swizzle
  int aoffs[2], boffs[2];
  #pragma unroll
  for (int kk = 0; kk < 2; ++kk) {
    aoffs[kk] = (wr * 128 + t16) * 64 + ((kk * 32 + quad * 8) ^ axr);
    boffs[kk] = (wc * 64 + t16) * 64 + ((kk * 32 + quad * 8) ^ axr);
  }

  f32x4 acc[8][4];
  #pragma unroll
  for (int i = 0; i < 8; ++i)
    #pragma unroll
    for (int j = 0; j < 4; ++j) acc[i][j] = (f32x4){0.f, 0.f, 0.f, 0.f};

  #define ST_B(bufi, tt) do {                                              \
    char* lb_ = (char*)&Bb[bufi][0] + wave * 1024;                         \
    _Pragma("unroll")                                                      \
    for (int q_ = 0; q_ < 4; ++q_)                                         \
      async_load16((const char*)Wt + bOff[q_] + (tt) * 128, lb_ + q_ * 8192); \
  } while (0)
  #define ST_A(bufi, tt) do {                                              \
    char* la_ = (char*)&Ab[bufi][0] + wave * 1024;                         \
    const int ka_ = ((tt) >> 2) * 512 + ((tt) & 3) * 128;                  \
    _Pragma("unroll")                                                      \
    for (int q_ = 0; q_ < 4; ++q_)                                         \
      async_load16((const char*)xpad + aOff[q_] + ka_, la_ + q_ * 8192);   \
  } while (0)

  ST_B(0, 0); ST_A(0, 0);
  ST_B(1, 1); ST_A(1, 1);
  asm volatile("s_waitcnt vmcnt(8)" ::: "memory");
  SCHED_FENCE();
  BARRIER();

  bf16x8 aLo[8], aHi[8], bLo[4], bHi[4];
  {
    const bf16* Ac = &Ab[0][0];
    const bf16* Bc = &Bb[0][0];
    #pragma unroll
    for (int i = 0; i < 4; ++i)
      #pragma unroll
      for (int kk = 0; kk < 2; ++kk)
        aLo[i * 2 + kk] = *(const bf16x8*)(Ac + aoffs[kk] + i * 1024);
    #pragma unroll
    for (int j = 0; j < 2; ++j)
      #pragma unroll
      for (int kk = 0; kk < 2; ++kk)
        bLo[j * 2 + kk] = *(const bf16x8*)(Bc + boffs[kk] + j * 1024);
  }
  SCHED_FENCE();

  for (int u = 0; u < 12; ++u) {
    const int buf = u & 1;
    const bf16* Ac = &Ab[buf][0];
    const bf16* Bc = &Bb[buf][0];
    const bf16* Ac2 = &Ab[buf ^ 1][0];
    const bf16* Bc2 = &Bb[buf ^ 1][0];
    const int st = u + 2;

    // P0: issue bHi reads; MFMA (0,0)
    #pragma unroll
    for (int j = 0; j < 2; ++j)
      #pragma unroll
      for (int kk = 0; kk < 2; ++kk)
        bHi[j * 2 + kk] = *(const bf16x8*)(Bc + boffs[kk] + (2 + j) * 1024);
    SCHED_FENCE();
    __builtin_amdgcn_s_setprio(1);
    #pragma unroll
    for (int i = 0; i < 4; ++i)
      #pragma unroll
      for (int j = 0; j < 2; ++j)
        #pragma unroll
        for (int kk = 0; kk < 2; ++kk)
          acc[i][j] = __builtin_amdgcn_mfma_f32_16x16x32_bf16(
              aLo[i * 2 + kk], bLo[j * 2 + kk], acc[i][j], 0, 0, 0);
    __builtin_amdgcn_s_setprio(0);
    SCHED_FENCE();

    // P1: issue aHi reads; MFMA (0,1)
    #pragma unroll
    for (int i = 0; i < 4; ++i)
      #pragma unroll
      for (int kk = 0; kk < 2; ++kk)
        aHi[i * 2 + kk] = *(const bf16x8*)(Ac + aoffs[kk] + (4 + i) * 1024);
    SCHED_FENCE();
    __builtin_amdgcn_s_setprio(1);
    #pragma unroll
    for (int i = 0; i < 4; ++i)
      #pragma unroll
      for (int j = 0; j < 2; ++j)
        #pragma unroll
        for (int kk = 0; kk < 2; ++kk)
          acc[i][2 + j] = __builtin_amdgcn_mfma_f32_16x16x32_bf16(
              aLo[i * 2 + kk], bHi[j * 2 + kk], acc[i][2 + j], 0, 0, 0);
    __builtin_amdgcn_s_setprio(0);
    SCHED_FENCE();

    // P2: barrier (B-region safe); stage B(u+2); MFMA (1,0)
    BARRIER();
    if (st < 12) ST_B(buf, st);
    SCHED_FENCE();
    __builtin_amdgcn_s_setprio(1);
    #pragma unroll
    for (int i = 0; i < 4; ++i)
      #pragma unroll
      for (int j = 0; j < 2; ++j)
        #pragma unroll
        for (int kk = 0; kk < 2; ++kk)
          acc[4 + i][j] = __builtin_amdgcn_mfma_f32_16x16x32_bf16(
              aHi[i * 2 + kk], bLo[j * 2 + kk], acc[4 + i][j], 0, 0, 0);
    __builtin_amdgcn_s_setprio(0);
    SCHED_FENCE();

    // P3: counted vmcnt + barrier; stage A(u+2); pre-issue next aLo/bLo; MFMA (1,1)
    if (u < 11) {
      if (u < 10) {
        asm volatile("s_waitcnt vmcnt(4)" ::: "memory");
      } else {
        asm volatile("s_waitcnt vmcnt(0)" ::: "memory");
      }
      SCHED_FENCE();
      BARRIER();
      if (st < 12) ST_A(buf, st);
      #pragma unroll
      for (int i = 0; i < 4; ++i)
        #pragma unroll
        for (int kk = 0; kk < 2; ++kk)
          aLo[i * 2 + kk] = *(const bf16x8*)(Ac2 + aoffs[kk] + i * 1024);
      #pragma unroll
      for (int j = 0; j < 2; ++j)
        #pragma unroll
        for (int kk = 0; kk < 2; ++kk)
          bLo[j * 2 + kk] = *(const bf16x8*)(Bc2 + boffs[kk] + j * 1024);
      SCHED_FENCE();
    }
    __builtin_amdgcn_s_setprio(1);
    #pragma unroll
    for (int i = 0; i < 4; ++i)
      #pragma unroll
      for (int j = 0; j < 2; ++j)
        #pragma unroll
        for (int kk = 0; kk < 2; ++kk)
          acc[4 + i][2 + j] = __builtin_amdgcn_mfma_f32_16x16x32_bf16(
              aHi[i * 2 + kk], bHi[j * 2 + kk], acc[4 + i][2 + j], 0, 0, 0);
    __builtin_amdgcn_s_setprio(0);
    SCHED_FENCE();
  }
  #undef ST_A
  #undef ST_B

  #pragma unroll
  for (int i = 0; i < 8; ++i)
    #pragma unroll
    for (int j = 0; j < 4; ++j) {
      const int col = n0 + wc * 64 + j * 16 + t16;
      #pragma unroll
      for (int r = 0; r < 4; ++r) {
        const int rowm = m0 + wr * 128 + i * 16 + quad * 4 + r;
        conv[(size_t)rowm * 768 + col] = (bf16)acc[i][j][r];
      }
    }
}

// ---------- fused LN + residual + masked attention + output projection ----------
// One block per batch. Stages the 25x768 bf16 qkv slab, LayerNorms in-place to
// f16, does the masked attention per (head, node) lane, writes attn-out (f16)
// into the then-dead q region of the SAME LDS slab (XOR-swizzled), then does
// out = attnout @ wo^T + bo via f16 MFMA with B from the fragment-ordered woF
// table (coalesced 16B/lane global reads, L2-hot). No attn HBM round-trip.
// Race-freedom of the in-place Ao write: head h writes q-region cols
// [h*32, h*32+32), which only lane (h,i) itself reads (its qv load, earlier in
// its own program order). Different heads' ranges are disjoint.
__global__ __launch_bounds__(256, 4) void k_attn_oproj(
    const bf16* __restrict__ conv, const float* __restrict__ x,
    const float* __restrict__ gq, const float* __restrict__ bq,
    const float* __restrict__ gk, const float* __restrict__ bk,
    const float* __restrict__ gv, const float* __restrict__ bv,
    const float* __restrict__ mb, const h16* __restrict__ woF,
    const float* __restrict__ bo, float* __restrict__ out) {
  __shared__ bf16 Cs[19456];     // 38912 B: 38 x 1024B chunks (25*768=19200 used)
  const int b = blockIdx.x;
  const int tid = threadIdx.x;
  const int wave = tid >> 6, lane = tid & 63;

  // blanket stage of the batch slab (contiguous 38400 B, over-staged to 38912 B)
  const char* slab = (const char*)(conv + (size_t)b * 19200);
  for (int c = wave; c < 38; c += 4)
    async_load16(slab + c * 1024 + lane * 16, (char*)Cs + c * 1024);
  asm volatile("s_waitcnt vmcnt(0)" ::: "memory");
  __syncthreads();

  // phase 1: LN + residual for 75 rows (node n, proj p), one wave per row
  for (int rowi = wave; rowi < 75; rowi += 4) {
    int n = rowi / 3;
    int p = rowi - n * 3;
    const int off = n * 768 + p * 256 + lane * 4;
    bf16x4 cv = *(const bf16x4*)(Cs + off);
    float v0 = (float)cv[0], v1 = (float)cv[1], v2 = (float)cv[2], v3 = (float)cv[3];
    float s = v0 + v1 + v2 + v3;
    float ss = v0 * v0 + v1 * v1 + v2 * v2 + v3 * v3;
    #pragma unroll
    for (int o = 32; o; o >>= 1) {
      s += __shfl_xor(s, o);
      ss += __shfl_xor(ss, o);
    }
    float mu = s * (1.0f / 256.0f);
    float var = ss * (1.0f / 256.0f) - mu * mu;
    float rs = rsqrtf(var + 1e-5f);
    const float* gsel = (p == 0) ? gq : ((p == 1) ? gk : gv);
    const float* bsel = (p == 0) ? bq : ((p == 1) ? bk : bv);
    const int dbase = lane * 4;
    f32x4 gg = *(const f32x4*)(gsel + dbase);
    f32x4 b2 = *(const f32x4*)(bsel + dbase);
    f32x4 xv = *(const f32x4*)(x + ((size_t)(b * 25 + n)) * 256 + dbase);
    h16x4 o;
    o[0] = (h16)((v0 - mu) * rs * gg[0] + b2[0] + xv[0]);
    o[1] = (h16)((v1 - mu) * rs * gg[1] + b2[1] + xv[1]);
    o[2] = (h16)((v2 - mu) * rs * gg[2] + b2[2] + xv[2]);
    o[3] = (h16)((v3 - mu) * rs * gg[3] + b2[3] + xv[3]);
    *(h16x4*)((h16*)Cs + off) = o;   // in-place bf16 -> f16, per-lane 8B
  }
  __syncthreads();

  // phase 2: one lane per (head, query-node); attn-out -> q region (swizzled f16)
  const h16* Ch = (const h16*)Cs;
  if (tid < HH * NN) {
    const int h = tid / 25;
    const int i = tid - h * 25;

    h16x2 qv[16];
    const h16x2* qp = (const h16x2*)(Ch + i * 768 + h * 32);
    #pragma unroll
    for (int c = 0; c < 16; ++c) qv[c] = qp[c];

    float mrow[28];
    const float* mbp = mb + (h * 25 + i) * 32;
    #pragma unroll
    for (int c = 0; c < 7; ++c) *(f32x4*)(mrow + c * 4) = *(const f32x4*)(mbp + c * 4);

    const float scale = 0.17677669529663687f;  // 1/sqrt(32)
    float sc[25];
    #pragma unroll
    for (int m = 0; m < 25; ++m) {
      const h16x2* kr = (const h16x2*)(Ch + m * 768 + 256 + h * 32);
      float d = 0.f;
      #pragma unroll
      for (int c = 0; c < 16; ++c)
        d = __builtin_amdgcn_fdot2(qv[c], kr[c], d, false);
      sc[m] = d * scale + mrow[m];
    }

    float mx = sc[0];
    #pragma unroll
    for (int m = 1; m < 25; ++m) mx = fmaxf(mx, sc[m]);
    float sum = 0.f;
    #pragma unroll
    for (int m = 0; m < 25; ++m) { sc[m] = __expf(sc[m] - mx); sum += sc[m]; }
    const float inv = 1.0f / sum;

    h16x2 acc[16];
    #pragma unroll
    for (int j = 0; j < 16; ++j) acc[j] = (h16x2){(h16)0.f, (h16)0.f};
    #pragma unroll
    for (int m = 0; m < 25; ++m) {
      h16 w = (h16)(sc[m] * inv);
      h16x2 wp = {w, w};
      const h16x2* vr = (const h16x2*)(Ch + m * 768 + 512 + h * 32);
      #pragma unroll
      for (int j = 0; j < 16; ++j)
        acc[j] = wp * vr[j] + acc[j];   // v_pk_fma_f16
    }

    // write attn-out into the dead q region, XOR-swizzled (read side matches)
    #pragma unroll
    for (int c = 0; c < 4; ++c) {
      h16x8 o;
      #pragma unroll
      for (int j = 0; j < 4; ++j) {
        o[2 * j]     = acc[c * 4 + j][0];
        o[2 * j + 1] = acc[c * 4 + j][1];
      }
      const int byteoff = i * 1536 + ((h * 64 + c * 16) ^ ((i & 7) << 4));
      *(h16x8*)((char*)Cs + byteoff) = o;
    }
  }
  __syncthreads();

  // phase 3: out[25,256] = Ao[25,256] @ wo^T + bo, f16 MFMA, per wave 4 N-tiles
  {
    const int t16 = lane & 15, quad = lane >> 4;
    f32x4 oacc[2][4];
    #pragma unroll
    for (int mt = 0; mt < 2; ++mt)
      #pragma unroll
      for (int jj = 0; jj < 4; ++jj) oacc[mt][jj] = (f32x4){0.f, 0.f, 0.f, 0.f};
    const int arow0 = t16;
    const int arow1 = (16 + t16 > 24) ? 24 : 16 + t16;   // clamp: rows 25..31 unused
    #pragma unroll
    for (int ks = 0; ks < 8; ++ks) {
      h16x8 aF0, aF1;
      {
        const int kb = ks * 64 + quad * 16;
        aF0 = *(const h16x8*)((const char*)Cs + arow0 * 1536 + (kb ^ ((arow0 & 7) << 4)));
        aF1 = *(const h16x8*)((const char*)Cs + arow1 * 1536 + (kb ^ ((arow1 & 7) << 4)));
      }
      #pragma unroll
      for (int jj = 0; jj < 4; ++jj) {
        const h16x8 bF = *(const h16x8*)(woF + ((ks * 16 + wave * 4 + jj) << 9) + lane * 8);
        oacc[0][jj] = __builtin_amdgcn_mfma_f32_16x16x32_f16(aF0, bF, oacc[0][jj], 0, 0, 0);
        oacc[1][jj] = __builtin_amdgcn_mfma_f32_16x16x32_f16(aF1, bF, oacc[1][jj], 0, 0, 0);
      }
    }
    #pragma unroll
    for (int jj = 0; jj < 4; ++jj) {
      const int col = (wave * 4 + jj) * 16 + t16;
      const float bb = bo[col];
      #pragma unroll
      for (int mt = 0; mt < 2; ++mt)
        #pragma unroll
        for (int r = 0; r < 4; ++r) {
          const int row = mt * 16 + quad * 4 + r;
          if (row < 25)
            out[((size_t)b * 25 + row) * 256 + col] = oacc[mt][jj][r] + bb;
        }
    }
  }
}

extern "C" void kernel_launch(void* const* d_in, const int* in_sizes, int n_in,
                              void* d_out, int out_size, void* d_ws, size_t ws_size,
                              hipStream_t stream) {
  (void)in_sizes; (void)n_in; (void)out_size; (void)ws_size;
  const float* x  = (const float*)d_in[0];
  const void*  adj = d_in[1];
  const float* wq = (const float*)d_in[2];
  const float* wk = (const float*)d_in[3];
  const float* wv = (const float*)d_in[4];
  const float* gq = (const float*)d_in[5];
  const float* bq = (const float*)d_in[6];
  const float* gk = (const float*)d_in[7];
  const float* bk = (const float*)d_in[8];
  const float* gv = (const float*)d_in[9];
  const float* bv = (const float*)d_in[10];
  const float* rel = (const float*)d_in[11];
  const float* lb = (const float*)d_in[12];
  const float* wo = (const float*)d_in[13];
  const float* bo = (const float*)d_in[14];
  float* out = (float*)d_out;

  char* ws = (char*)d_ws;
  size_t off = 0;
  auto alloc = [&](size_t bytes) -> void* {
    void* p = ws + off;
    off += (bytes + 255) & ~(size_t)255;
    return p;
  };
  bf16* xpad = (bf16*)alloc((size_t)BB * 27 * 256 * 2);    // 56.6 MB
  bf16* conv = (bf16*)alloc((size_t)MM * 768 * 2);         // 157.3 MB
  bf16* Wt   = (bf16*)alloc((size_t)768 * 768 * 2);
  h16*  woF  = (h16*)alloc((size_t)65536 * 2);             // 128 KB fragment-order wo
  float* mb  = (float*)alloc((size_t)HH * NN * 32 * 4);

  hipLaunchKernelGGL(k_prep, dim3(14336), dim3(256), 0, stream,
                     x, xpad, wq, wk, wv, rel, lb, wo, adj, Wt, woF, mb);
  hipLaunchKernelGGL(k_qkv_gemm8, dim3(1200), dim3(512), 0, stream, xpad, Wt, conv);
  hipLaunchKernelGGL(k_attn_oproj, dim3(4096), dim3(256), 0, stream,
                     conv, x, gq, bq, gk, bk, gv, bv, mb, woF, bo, out);
}